// Round 1
// baseline (434.281 us; speedup 1.0000x reference)
//
#include <hip/hip_runtime.h>
#include <hip/hip_bf16.h>

// MTSiLU: out = (w[c, bin(x)] * x + b[c, bin(x)]) * sigmoid(x)
// x: [B=16, C=64, H=256, W=256] fp32; weight/bias: [64, 20] fp32.
// Element-wise, HBM-bound: ~537 MB total traffic -> ~85-95 us floor.

#define MT_C 64
#define MT_BINS 20
#define MT_TABLE (MT_C * MT_BINS)   // 1280 floats per table

// One channel plane = 256*256 = 65536 elems = 16384 float4.
// float4 index i -> channel = (i >> 14) & 63.

__global__ __launch_bounds__(256) void mtsilu_kernel(
    const float4* __restrict__ x,
    const float* __restrict__ weight,
    const float* __restrict__ bias,
    float4* __restrict__ out,
    int nvec)
{
    __shared__ float sw[MT_TABLE];
    __shared__ float sb[MT_TABLE];
    for (int i = threadIdx.x; i < MT_TABLE; i += 256) {
        sw[i] = weight[i];
        sb[i] = bias[i];
    }
    __syncthreads();

    const int stride = gridDim.x * 256;
    for (int i = blockIdx.x * 256 + threadIdx.x; i < nvec; i += stride) {
        float4 v = x[i];
        const int cbase = ((i >> 14) & (MT_C - 1)) * MT_BINS;

        float r[4];
        float xv[4] = {v.x, v.y, v.z, v.w};
        #pragma unroll
        for (int k = 0; k < 4; ++k) {
            float xk = xv[k];
            int idx = (int)floorf(xk * 10.0f) + (MT_BINS / 2);
            idx = idx < 0 ? 0 : (idx > MT_BINS - 1 ? MT_BINS - 1 : idx);
            float wv = sw[cbase + idx];
            float bv = sb[cbase + idx];
            float s = 1.0f / (1.0f + __expf(-xk));
            r[k] = (wv * xk + bv) * s;
        }
        float4 o;
        o.x = r[0]; o.y = r[1]; o.z = r[2]; o.w = r[3];
        out[i] = o;
    }
}

extern "C" void kernel_launch(void* const* d_in, const int* in_sizes, int n_in,
                              void* d_out, int out_size, void* d_ws, size_t ws_size,
                              hipStream_t stream) {
    const float4* x      = (const float4*)d_in[0];
    const float*  weight = (const float*)d_in[1];
    const float*  bias   = (const float*)d_in[2];
    float4*       out    = (float4*)d_out;

    const int n    = in_sizes[0];        // 16*64*256*256 = 67108864
    const int nvec = n / 4;              // 16777216 float4

    // 16384 blocks x 256 threads = 4M threads, 4 float4 each (grid-stride).
    const int block = 256;
    const int grid  = 16384;
    mtsilu_kernel<<<grid, block, 0, stream>>>(x, weight, bias, out, nvec);
}